// Round 1
// baseline (494.958 us; speedup 1.0000x reference)
//
#include <hip/hip_runtime.h>
#include <stdint.h>

// Problem constants
#define A_    10
#define NPA_  192
#define C_    128
#define N_    1920      // A_*NPA_
#define M_    32768     // B*T
#define OUTC  1280      // A_*C_
#define MT    16        // rows per block tile
#define RS    1928      // padded LDS row stride in bf16 elems (1920+8 -> 16B-aligned rows, stride%32dw==4 -> 2-way max on b128)

typedef __attribute__((ext_vector_type(8))) short  short8;
typedef __attribute__((ext_vector_type(4))) float  float4v;

__device__ __forceinline__ unsigned short f2bf(float f) {
  unsigned u = __builtin_bit_cast(unsigned, f);
  u += 0x7FFFu + ((u >> 16) & 1u);           // round-to-nearest-even
  return (unsigned short)(u >> 16);
}

// Block 0 / wave 0: build dest[p] = a*192 + rank(p within area a), matching np.where ascending order.
// Blocks 1..960: transpose W (A,NPA,C) fp32 -> Wt[a][c][k] bf16.
__global__ __launch_bounds__(256) void prep_kernel(const float* __restrict__ W,
                                                   const int* __restrict__ nr,
                                                   unsigned short* __restrict__ Wt,
                                                   int* __restrict__ dest) {
  if (blockIdx.x == 0) {
    int lane = threadIdx.x;
    if (lane < 64) {
      int cnt[A_];
#pragma unroll
      for (int i = 0; i < A_; ++i) cnt[i] = 0;
      unsigned long long lt = (1ull << lane) - 1ull;
      for (int ch = 0; ch < N_ / 64; ++ch) {
        int p = ch * 64 + lane;
        int a = nr[p];
        int base = 0, rank = 0;
#pragma unroll
        for (int aa = 0; aa < A_; ++aa) {
          unsigned long long m = __ballot(a == aa);
          if (a == aa) { base = cnt[aa]; rank = __popcll(m & lt); }
          cnt[aa] += __popcll(m);
        }
        dest[p] = a * NPA_ + base + rank;
      }
    }
  } else {
    int o  = (blockIdx.x - 1) * 256 + threadIdx.x;   // 0..245759 exactly
    int ac = o / NPA_;
    int k  = o - ac * NPA_;
    int a  = ac >> 7;
    int c  = ac & 127;
    Wt[o] = f2bf(W[(a * NPA_ + k) * C_ + c]);
  }
}

// Main: per block (1024 threads = 16 waves), stage 16 rows x 1920 cols of x (contiguous
// global range) as bf16 scattered into permuted LDS layout xs[m][a*192+n]; then 16 waves
// x 5 (area,ctile) 16x16 output tiles, K=192 via 6x mfma_f32_16x16x32_bf16.
// LDS 61,952B -> 2 blocks/CU -> 32 waves/CU (was 8 with 256-thread blocks): the kernel is
// latency-bound (MfmaUtil 3%, VALUBusy 12%, occupancy 22%), so quadruple the resident waves.
#define STAGE_BODY(gexpr)                                                    \
  do {                                                                       \
    int g_  = (gexpr);                                                       \
    int row = g_ / 480;                                                      \
    int c4  = g_ - row * 480;                                                \
    float4 v = xp[g_];                                                       \
    int4   d = dp[c4];                                                       \
    unsigned short* base = xs + row * RS;                                    \
    base[d.x] = f2bf(v.x);                                                   \
    base[d.y] = f2bf(v.y);                                                   \
    base[d.z] = f2bf(v.z);                                                   \
    base[d.w] = f2bf(v.w);                                                   \
  } while (0)

__global__ __launch_bounds__(1024, 8) void stitch_kernel(const float* __restrict__ x,
                                                         const unsigned short* __restrict__ Wt,
                                                         const float* __restrict__ bias,
                                                         const int* __restrict__ dest,
                                                         float* __restrict__ out) {
  __shared__ unsigned short xs[MT * RS];   // 61,696 B -> 2 blocks/CU

  const int tid = threadIdx.x;
  const int mb  = blockIdx.x * MT;

  // ---- stage x tile (coalesced float4 reads, bf16 scatter writes) ----
  // 7680 float4s, 1024 threads: 7 full rounds + half-round tail.
  const float4* xp = (const float4*)(x + (size_t)mb * N_);
  const int4*   dp = (const int4*)dest;
#pragma unroll
  for (int i = 0; i < 7; ++i) STAGE_BODY(i * 1024 + tid);
  if (tid < 512) STAGE_BODY(7168 + tid);
  __syncthreads();

  const int wave = tid >> 6;
  const int lane = tid & 63;
  const int l15  = lane & 15;
  const int lq   = lane >> 4;

  short8 af[6];
  int    cur_a = -1;
  const int t0 = wave * 5;               // 80 tiles / 16 waves

  // prefetch B-fragments for first tile
  short8 bf[6];
  {
    int t = t0, a = t >> 3, cc = t & 7;
    const short8* wp = (const short8*)(Wt + (size_t)(a * C_ + cc * 16 + l15) * NPA_);
#pragma unroll
    for (int ks = 0; ks < 6; ++ks) bf[ks] = wp[ks * 4 + lq];
  }

  for (int t = t0; t < t0 + 5; ++t) {
    int a = t >> 3, cc = t & 7;
    if (a != cur_a) {
#pragma unroll
      for (int ks = 0; ks < 6; ++ks)
        af[ks] = *(const short8*)&xs[l15 * RS + a * NPA_ + ks * 32 + lq * 8];
      cur_a = a;
    }
    float bv = bias[a * C_ + cc * 16 + l15];

    short8 bfn[6];
    if (t + 1 < t0 + 5) {
      int t2 = t + 1, a2 = t2 >> 3, cc2 = t2 & 7;
      const short8* wp2 = (const short8*)(Wt + (size_t)(a2 * C_ + cc2 * 16 + l15) * NPA_);
#pragma unroll
      for (int ks = 0; ks < 6; ++ks) bfn[ks] = wp2[ks * 4 + lq];
    }

    float4v acc = {0.f, 0.f, 0.f, 0.f};
#pragma unroll
    for (int ks = 0; ks < 6; ++ks)
      acc = __builtin_amdgcn_mfma_f32_16x16x32_bf16(af[ks], bf[ks], acc, 0, 0, 0);

    // C/D layout: col = lane&15, row = (lane>>4)*4 + r
    float* op = out + (size_t)(mb + lq * 4) * OUTC + a * C_ + cc * 16 + l15;
#pragma unroll
    for (int r = 0; r < 4; ++r) op[(size_t)r * OUTC] = acc[r] + bv;

#pragma unroll
    for (int ks = 0; ks < 6; ++ks) bf[ks] = bfn[ks];
  }
}

extern "C" void kernel_launch(void* const* d_in, const int* in_sizes, int n_in,
                              void* d_out, int out_size, void* d_ws, size_t ws_size,
                              hipStream_t stream) {
  const float* x    = (const float*)d_in[0];   // (32,1024,1920) f32
  const float* W    = (const float*)d_in[1];   // (10,192,128)   f32
  const float* b    = (const float*)d_in[2];   // (10,128)       f32
  const int*   nr   = (const int*)  d_in[3];   // (32,1920) int32 (row 0 used)
  float*       out  = (float*)d_out;           // (32,1024,1280) f32

  unsigned short* Wt   = (unsigned short*)d_ws;                  // 491,520 B
  int*            dest = (int*)((char*)d_ws + 491520);           // 7,680 B

  prep_kernel<<<dim3(961), dim3(256), 0, stream>>>(W, nr, Wt, dest);
  stitch_kernel<<<dim3(M_ / MT), dim3(1024), 0, stream>>>(x, Wt, b, dest, out);
}

// Round 2
// 452.586 us; speedup vs baseline: 1.0936x; 1.0936x over previous
//
#include <hip/hip_runtime.h>
#include <stdint.h>

// Problem constants
#define A_    10
#define NPA_  192
#define C_    128
#define N_    1920      // A_*NPA_
#define M_    32768     // B*T
#define OUTC  1280      // A_*C_
#define MT    32        // rows per block tile (32: each wave reuses Wt fragments across both 16-row halves)
#define RS    1928      // padded LDS row stride in bf16 elems (stride%32dw==4 -> 2-way max on b128)
#define LDS_BYTES (MT*RS*2 + N_*4)   // 123392 + 7680 = 131072

typedef __attribute__((ext_vector_type(8))) short  short8;
typedef __attribute__((ext_vector_type(4))) float  float4v;

__device__ __forceinline__ unsigned short f2bf(float f) {
  unsigned u = __builtin_bit_cast(unsigned, f);
  u += 0x7FFFu + ((u >> 16) & 1u);           // round-to-nearest-even
  return (unsigned short)(u >> 16);
}

// Block 0 / wave 0: build dest[p] = a*192 + rank(p within area a), matching np.where ascending order.
// Blocks 1..960: transpose W (A,NPA,C) fp32 -> Wt[a][c][k] bf16.
__global__ __launch_bounds__(256) void prep_kernel(const float* __restrict__ W,
                                                   const int* __restrict__ nr,
                                                   unsigned short* __restrict__ Wt,
                                                   int* __restrict__ dest) {
  if (blockIdx.x == 0) {
    int lane = threadIdx.x;
    if (lane < 64) {
      int cnt[A_];
#pragma unroll
      for (int i = 0; i < A_; ++i) cnt[i] = 0;
      unsigned long long lt = (1ull << lane) - 1ull;
      for (int ch = 0; ch < N_ / 64; ++ch) {
        int p = ch * 64 + lane;
        int a = nr[p];
        int base = 0, rank = 0;
#pragma unroll
        for (int aa = 0; aa < A_; ++aa) {
          unsigned long long m = __ballot(a == aa);
          if (a == aa) { base = cnt[aa]; rank = __popcll(m & lt); }
          cnt[aa] += __popcll(m);
        }
        dest[p] = a * NPA_ + base + rank;
      }
    }
  } else {
    int o  = (blockIdx.x - 1) * 256 + threadIdx.x;   // 0..245759 exactly
    int ac = o / NPA_;
    int k  = o - ac * NPA_;
    int a  = ac >> 7;
    int c  = ac & 127;
    Wt[o] = f2bf(W[(a * NPA_ + k) * C_ + c]);
  }
}

// Main: per block (1024 threads = 16 waves), stage 32 rows x 1920 cols of x as bf16
// scattered into permuted LDS layout xs[m][a*192+n]; dest table cached in LDS.
// Each wave owns 5 (area,ctile) pairs and computes BOTH 16-row halves per pair with the
// same register-held B-fragments -> Wt vmem traffic per output row is halved vs MT=16.
// Rationale: perf was invariant to occupancy (8 vs 23 waves/CU identical) -> per-CU vmem
// throughput is the binder; Wt fragment re-streaming was 60% of per-CU vmem bytes.
__global__ __launch_bounds__(1024, 4) void stitch_kernel(const float* __restrict__ x,
                                                         const unsigned short* __restrict__ Wt,
                                                         const float* __restrict__ bias,
                                                         const int* __restrict__ dest,
                                                         float* __restrict__ out) {
  extern __shared__ char smem[];
  unsigned short* xs   = (unsigned short*)smem;        // [MT][RS] bf16
  int*            dlds = (int*)(smem + MT * RS * 2);   // [N_] dest table

  const int tid = threadIdx.x;
  const int mb  = blockIdx.x * MT;

  // ---- cache dest table in LDS (kills 123KB/block of global dest re-reads) ----
  if (tid < 480) ((int4*)dlds)[tid] = ((const int4*)dest)[tid];
  __syncthreads();

  // ---- stage x tile (coalesced float4 reads, bf16 scatter writes) ----
  // 15,360 float4s / 1024 threads = 15 exact rounds.
  const float4* xp = (const float4*)(x + (size_t)mb * N_);
#pragma unroll
  for (int i = 0; i < 15; ++i) {
    int g   = i * 1024 + tid;
    int row = g / 480;
    int c4  = g - row * 480;
    float4 v = xp[g];
    int4   d = ((const int4*)dlds)[c4];
    unsigned short* base = xs + row * RS;
    base[d.x] = f2bf(v.x);
    base[d.y] = f2bf(v.y);
    base[d.z] = f2bf(v.z);
    base[d.w] = f2bf(v.w);
  }
  __syncthreads();

  const int wave = tid >> 6;
  const int lane = tid & 63;
  const int l15  = lane & 15;
  const int lq   = lane >> 4;

  short8 af0[6], af1[6];
  int    cur_a = -1;
  const int p0 = wave * 5;               // 80 (area,ctile) pairs / 16 waves

  // prefetch B-fragments for first pair
  short8 bf[6];
  {
    int p = p0, a = p >> 3, cc = p & 7;
    const short8* wp = (const short8*)(Wt + (size_t)(a * C_ + cc * 16 + l15) * NPA_);
#pragma unroll
    for (int ks = 0; ks < 6; ++ks) bf[ks] = wp[ks * 4 + lq];
  }

  for (int p = p0; p < p0 + 5; ++p) {
    int a = p >> 3, cc = p & 7;
    if (a != cur_a) {
#pragma unroll
      for (int ks = 0; ks < 6; ++ks) {
        af0[ks] = *(const short8*)&xs[l15 * RS + a * NPA_ + ks * 32 + lq * 8];
        af1[ks] = *(const short8*)&xs[(16 + l15) * RS + a * NPA_ + ks * 32 + lq * 8];
      }
      cur_a = a;
    }
    float bv = bias[a * C_ + cc * 16 + l15];

    short8 bfn[6];
    if (p + 1 < p0 + 5) {
      int p2 = p + 1, a2 = p2 >> 3, cc2 = p2 & 7;
      const short8* wp2 = (const short8*)(Wt + (size_t)(a2 * C_ + cc2 * 16 + l15) * NPA_);
#pragma unroll
      for (int ks = 0; ks < 6; ++ks) bfn[ks] = wp2[ks * 4 + lq];
    }

    float4v acc0 = {0.f, 0.f, 0.f, 0.f};
    float4v acc1 = {0.f, 0.f, 0.f, 0.f};
#pragma unroll
    for (int ks = 0; ks < 6; ++ks) {
      acc0 = __builtin_amdgcn_mfma_f32_16x16x32_bf16(af0[ks], bf[ks], acc0, 0, 0, 0);
      acc1 = __builtin_amdgcn_mfma_f32_16x16x32_bf16(af1[ks], bf[ks], acc1, 0, 0, 0);
    }

    // C/D layout: col = lane&15, row = (lane>>4)*4 + r
    float* op0 = out + (size_t)(mb + lq * 4) * OUTC + a * C_ + cc * 16 + l15;
    float* op1 = op0 + (size_t)16 * OUTC;
#pragma unroll
    for (int r = 0; r < 4; ++r) {
      op0[(size_t)r * OUTC] = acc0[r] + bv;
      op1[(size_t)r * OUTC] = acc1[r] + bv;
    }

#pragma unroll
    for (int ks = 0; ks < 6; ++ks) bf[ks] = bfn[ks];
  }
}

extern "C" void kernel_launch(void* const* d_in, const int* in_sizes, int n_in,
                              void* d_out, int out_size, void* d_ws, size_t ws_size,
                              hipStream_t stream) {
  const float* x    = (const float*)d_in[0];   // (32,1024,1920) f32
  const float* W    = (const float*)d_in[1];   // (10,192,128)   f32
  const float* b    = (const float*)d_in[2];   // (10,128)       f32
  const int*   nr   = (const int*)  d_in[3];   // (32,1920) int32 (row 0 used)
  float*       out  = (float*)d_out;           // (32,1024,1280) f32

  unsigned short* Wt   = (unsigned short*)d_ws;                  // 491,520 B
  int*            dest = (int*)((char*)d_ws + 491520);           // 7,680 B

  static int lds_attr_set = 0;
  if (!lds_attr_set) {
    hipFuncSetAttribute((const void*)stitch_kernel,
                        hipFuncAttributeMaxDynamicSharedMemorySize, LDS_BYTES);
    lds_attr_set = 1;
  }

  prep_kernel<<<dim3(961), dim3(256), 0, stream>>>(W, nr, Wt, dest);
  stitch_kernel<<<dim3(M_ / MT), dim3(1024), LDS_BYTES, stream>>>(x, Wt, b, dest, out);
}